// Round 5
// baseline (117.294 us; speedup 1.0000x reference)
//
#include <hip/hip_runtime.h>
#include <hip/hip_bf16.h>

typedef __bf16 bf16x8 __attribute__((ext_vector_type(8)));
typedef float floatx4 __attribute__((ext_vector_type(4)));

#define BATCH 256
#define INDIM 512
#define ODIM 10
#define HTOT 18432
#define NMODEL 128
#define HTILE 64
#define BTILE 64
#define BK 128                          // K elems per stage; row = 256 B = 16 chunks of 16 B
#define ACT_CHUNK 4608
#define WCNT (HTOT * INDIM)             // bf16 elems of w
#define XCNT (BATCH * INDIM)            // bf16 elems of x
#define NJPG (HTOT / 32)                // 576 aligned 32-neuron groups

// async global->LDS, 16B per lane, dest = wave-uniform base + lane*16
#define GLOAD_LDS(gp, lp) __builtin_amdgcn_global_load_lds( \
    (const __attribute__((address_space(1))) unsigned int*)(const void*)(gp), \
    (__attribute__((address_space(3))) unsigned int*)(lp), 16, 0, 0)

__device__ __forceinline__ unsigned pk2(float a, float b) {
    unsigned ua = __float_as_uint(a);
    ua = (ua + 0x7fffu + ((ua >> 16) & 1u)) >> 16;
    unsigned ub = __float_as_uint(b);
    ub = (ub + 0x7fffu + ((ub >> 16) & 1u)) >> 16;
    return ua | (ub << 16);
}

__device__ __forceinline__ float apply_act(float h, int aidx) {
    if (aidx == 0) return fmaxf(h, 0.f);
    if (aidx == 1) return 1.f - 2.f / (1.f + __expf(2.f * h));   // tanh, no-overflow form
    if (aidx == 2) return 1.f / (1.f + __expf(-h));              // sigmoid
    return h;                                                     // identity
}

// fp32 -> bf16 (RNE) for hidden_w then x, 8 elems/thread, streaming.
__global__ __launch_bounds__(256) void convert_kernel(
    const float* __restrict__ hw, const float* __restrict__ x,
    unsigned short* __restrict__ dst)
{
    size_t i = (size_t)(blockIdx.x * 256 + threadIdx.x) * 8;
    const float* src = (i < (size_t)WCNT) ? hw + i : x + (i - WCNT);
    floatx4 v0 = *(const floatx4*)src;
    floatx4 v1 = *(const floatx4*)(src + 4);
    uint4 o;
    o.x = pk2(v0[0], v0[1]); o.y = pk2(v0[2], v0[3]);
    o.z = pk2(v1[0], v1[1]); o.w = pk2(v1[2], v1[3]);
    *(uint4*)(dst + i) = o;
}

// LDS tiles: 64 rows x 128 bf16 (256 B rows, 16 chunks of 16 B), XOR-swizzled:
// logical chunk c of row r is stored at chunk c ^ (r & 7)  ->  conflict-free
// ds_read_b128 fragment reads (2 lanes/bank) AND compatible with glds staging
// (glds dest fixed = base + lane*16; the lane just FETCHES the swizzled chunk).
// grid = 288 j-blocks * 4 b-blocks = 1152, 256 thr, 4 blocks/CU (35 KB LDS).
// Wave (jh,bh) computes quadrant 32j x 32b via acc[2][2] (16x16x32 bf16 MFMA).
__global__ __launch_bounds__(256, 4) void mlp_kernel(
    const unsigned short* __restrict__ wbf, const unsigned short* __restrict__ xbf,
    const float* __restrict__ hidden_b, const float* __restrict__ out_w,
    float* __restrict__ part)
{
    __shared__ __align__(16) unsigned short wsx[HTILE * BK];   // 16 KB
    __shared__ __align__(16) unsigned short xs[BTILE * BK];    // 16 KB
    __shared__ float wtile[ODIM * HTILE];                      // 2.5 KB, [o][64]
    __shared__ float btile[HTILE];

    const int tid = threadIdx.x;
    const int bid = blockIdx.x;
    const int jb = bid >> 2, bb = bid & 3;   // consecutive bids share the w-tile
    const int j0 = jb * HTILE;
    const int b0 = bb * BTILE;
    const int lane = tid & 63;
    const int wvid = tid >> 6;
    const int jh = wvid >> 1, bh = wvid & 1; // quadrant
    const int r = lane & 15;
    const int g = lane >> 4;

    // epilogue-only tiles (first __syncthreads covers them)
    for (int i = tid; i < ODIM * HTILE; i += 256)
        wtile[i] = out_w[(i >> 6) * HTOT + j0 + (i & 63)];
    if (tid < HTILE) btile[tid] = hidden_b[j0 + tid];

    floatx4 acc[2][2];
    #pragma unroll
    for (int jt = 0; jt < 2; jt++)
        #pragma unroll
        for (int bt = 0; bt < 2; bt++) acc[jt][bt] = (floatx4)0.f;

    // staging: wave stages rows [wvid*16, wvid*16+16) of each tile, 4 glds each.
    // glds #i covers LDS rows wvid*16 + i*4 .. +4 (4 rows x 256 B = 1024 B).
    // lane L -> dest row wvid*16 + i*4 + (L>>4), stored chunk sc = L&15;
    // fetch logical chunk c = sc ^ (row & 7).
    const int drow = lane >> 4;     // 0..3
    const int sc = lane & 15;
    const unsigned short* gw[4];
    const unsigned short* gx[4];
    #pragma unroll
    for (int i = 0; i < 4; i++) {
        int row = wvid * 16 + i * 4 + drow;
        int c = sc ^ (row & 7);
        gw[i] = wbf + (size_t)(j0 + row) * INDIM + c * 8;
        gx[i] = xbf + (size_t)(b0 + row) * INDIM + c * 8;
    }

    for (int kk = 0; kk < INDIM; kk += BK) {
        #pragma unroll
        for (int i = 0; i < 4; i++) {
            char* lw = (char*)wsx + (wvid * 16 + i * 4) * 256;   // wave-uniform
            char* lx = (char*)xs  + (wvid * 16 + i * 4) * 256;
            GLOAD_LDS(gw[i] + kk, lw);
            GLOAD_LDS(gx[i] + kk, lx);
        }
        __syncthreads();
        #pragma unroll
        for (int s = 0; s < 4; s++) {
            const int cx = (s * 4 + g) ^ (r & 7);   // swizzled chunk for this lane
            bf16x8 af[2], bfr[2];
            #pragma unroll
            for (int jt = 0; jt < 2; jt++)
                af[jt] = *(const bf16x8*)&wsx[(jh * 32 + jt * 16 + r) * BK + cx * 8];
            #pragma unroll
            for (int bt = 0; bt < 2; bt++)
                bfr[bt] = *(const bf16x8*)&xs[(bh * 32 + bt * 16 + r) * BK + cx * 8];
            #pragma unroll
            for (int jt = 0; jt < 2; jt++)
                #pragma unroll
                for (int bt = 0; bt < 2; bt++)
                    acc[jt][bt] = __builtin_amdgcn_mfma_f32_16x16x32_bf16(af[jt], bfr[bt], acc[jt][bt], 0, 0, 0);
        }
        __syncthreads();
    }

    // Epilogue. D layout: col(b) = lane&15, row(j within 16-tile) = g*4 + reg.
    // Wave (jh,bh) owns the full 32-j group jpg = j0/32 + jh for b-seg bh*32.
    const int aidx = j0 / ACT_CHUNK;             // uniform per block
    const int jpg = (j0 >> 5) + jh;

    float a[2][2][4];
    #pragma unroll
    for (int jt = 0; jt < 2; jt++)
        #pragma unroll
        for (int bt = 0; bt < 2; bt++)
            #pragma unroll
            for (int q = 0; q < 4; q++)
                a[jt][bt][q] = apply_act(acc[jt][bt][q] + btile[jh * 32 + jt * 16 + g * 4 + q], aidx);

    #pragma unroll
    for (int o = 0; o < ODIM; o++) {
        #pragma unroll
        for (int bt = 0; bt < 2; bt++) {
            float p = 0.f;
            #pragma unroll
            for (int jt = 0; jt < 2; jt++) {
                const float* wr = &wtile[o * HTILE + jh * 32 + jt * 16 + g * 4];
                p += a[jt][bt][0] * wr[0] + a[jt][bt][1] * wr[1]
                   + a[jt][bt][2] * wr[2] + a[jt][bt][3] * wr[3];
            }
            p += __shfl_xor(p, 16, 64);
            p += __shfl_xor(p, 32, 64);
            if (lane < 16) {
                int b = b0 + bh * 32 + bt * 16 + r;
                part[((size_t)jpg * ODIM + o) * BATCH + b] = p;   // one owner, plain store
            }
        }
    }
}

// One block per (model, o): 1280 blocks x 256 threads (thread = b).
__global__ __launch_bounds__(256) void finalize_kernel(
    const float* __restrict__ part, const float* __restrict__ out_b,
    float* __restrict__ out)
{
    const int mo = blockIdx.x;           // m*ODIM + o
    const int m = mo / ODIM, o = mo - m * ODIM;
    const int b = threadIdx.x;
    const int rep = m >> 3, idx = m & 7; // model m -> 32*(idx+1) neurons
    const int jp0 = rep * 36 + (idx * (idx + 1)) / 2;
    const int cnt = idx + 1;

    float s = out_b[mo];
    for (int c = 0; c < cnt; c++)
        s += part[((size_t)(jp0 + c) * ODIM + o) * BATCH + b];
    out[((size_t)b * NMODEL + m) * ODIM + o] = s;
}

extern "C" void kernel_launch(void* const* d_in, const int* in_sizes, int n_in,
                              void* d_out, int out_size, void* d_ws, size_t ws_size,
                              hipStream_t stream) {
    const float* x   = (const float*)d_in[0];
    const float* hw  = (const float*)d_in[1];
    const float* hb  = (const float*)d_in[2];
    const float* ow  = (const float*)d_in[3];
    const float* ob  = (const float*)d_in[4];
    float* out = (float*)d_out;

    unsigned short* wbf = (unsigned short*)d_ws;          // 18.9 MB
    unsigned short* xbf = wbf + WCNT;                     // 256 KB
    float* part = (float*)d_ws + (WCNT + XCNT) / 2;       // 5.9 MB, 16B-aligned

    convert_kernel<<<(WCNT + XCNT) / 8 / 256, 256, 0, stream>>>(hw, x, wbf);
    mlp_kernel<<<(HTOT / HTILE) * (BATCH / BTILE), 256, 0, stream>>>(wbf, xbf, hb, ow, part);
    finalize_kernel<<<NMODEL * ODIM, 256, 0, stream>>>(part, ob, out);
}